// Round 4
// baseline (2215.971 us; speedup 1.0000x reference)
//
#include <hip/hip_runtime.h>
#include <math.h>

using f32x4    = __attribute__((ext_vector_type(4))) float;
using short8   = __attribute__((ext_vector_type(8))) short;
using ushort8  = __attribute__((ext_vector_type(8))) unsigned short;
using ushort4v = __attribute__((ext_vector_type(4))) unsigned short;

#define D_DIM 768
#define H_DIM 3072

// ---------------- ws layout (bytes) ----------------
static const size_t HIST1_OFF = 0;                      // 2*65536*4 = 524288
static const size_t HIST2_OFF = 524288;                 // 4*65536*4 = 1048576 -> end 1572864
static const size_t SUM_OFF   = 1572864;                // double[2]
static const size_t THR_OFF   = 1572880;                // double[2]
static const size_t META_OFF  = 1572896;                // u32[16]
static const size_t ZERO_BYTES= 1572960;
static const size_t MU1_OFF   = 2097152;                // f32[32768]
static const size_t RS1_OFF   = MU1_OFF + 131072;
static const size_t MU2_OFF   = RS1_OFF + 131072;
static const size_t RS2_OFF   = MU2_OFF + 131072;
static const size_t WQ1_OFF   = 4194304;                // bf16[3072*768] = 4718592
static const size_t WQ2_OFF   = WQ1_OFF + 4718592;
static const size_t H1_OFF    = 16777216;               // bf16[32768*3072] = 201326592

// meta (u32 view): [0..1] pfxA[t], [2..3] remA[t], [4..5] pfxB[t], [6..7] remB[t]
// meta (f32 view): [8..9] scale[t]

__device__ __forceinline__ unsigned short f2bf(float f) {
    unsigned u = __float_as_uint(f);
    u += 0x7fffu + ((u >> 16) & 1u);
    return (unsigned short)(u >> 16);
}
__device__ __forceinline__ float bf2f(unsigned short s) {
    return __uint_as_float(((unsigned)s) << 16);
}

// ---------------- histogram of top-16 bits of |w| + fp64 abs-sum ----------------
__global__ void hist_abs_kernel(const float* __restrict__ W1, int n1,
                                const float* __restrict__ W2, int n2,
                                unsigned* __restrict__ hist, double* __restrict__ sums) {
    int tid = blockIdx.x * blockDim.x + threadIdx.x;
    int stride = gridDim.x * blockDim.x;
    for (int t = 0; t < 2; t++) {
        const float* W = t ? W2 : W1;
        int n = t ? n2 : n1;
        unsigned* h = hist + (size_t)t * 65536;
        double local = 0.0;
        int n4 = n >> 2;
        for (int i = tid; i < n4; i += stride) {
            f32x4 w = ((const f32x4*)W)[i];
#pragma unroll
            for (int j = 0; j < 4; j++) {
                float a = fabsf(w[j]);
                local += (double)a;
                atomicAdd(&h[__float_as_uint(a) >> 16], 1u);
            }
        }
        for (int i = (n4 << 2) + tid; i < n; i += stride) {
            float a = fabsf(W[i]);
            local += (double)a;
            atomicAdd(&h[__float_as_uint(a) >> 16], 1u);
        }
#pragma unroll
        for (int off = 32; off >= 1; off >>= 1) local += __shfl_down(local, off);
        if ((threadIdx.x & 63) == 0) atomicAdd(&sums[t], local);
    }
}

// ---------------- level-1 scan: find 16-bit prefix bucket for ranks k and k+1 ----------------
__global__ void scan1_kernel(const unsigned* __restrict__ hist, unsigned* __restrict__ meta_u,
                             const float* __restrict__ sparsity, int n1, int n2) {
    __shared__ unsigned partial[256];
    __shared__ unsigned basearr[256];
    for (int t = 0; t < 2; t++) {
        const unsigned* h = hist + (size_t)t * 65536;
        int n = t ? n2 : n1;
        double p = (double)(*sparsity) * (double)(n - 1);
        unsigned kA = (unsigned)floor(p);
        unsigned kB = kA + 1; if (kB > (unsigned)(n - 1)) kB = (unsigned)(n - 1);
        int b0 = threadIdx.x * 256;
        unsigned s_local = 0;
        for (int b = 0; b < 256; b++) s_local += h[b0 + b];
        partial[threadIdx.x] = s_local;
        __syncthreads();
        if (threadIdx.x == 0) {
            unsigned run = 0;
            for (int i = 0; i < 256; i++) { unsigned tmp = partial[i]; basearr[i] = run; run += tmp; }
        }
        __syncthreads();
        unsigned cumbase = basearr[threadIdx.x];
        for (int s = 0; s < 2; s++) {
            unsigned rank = s ? kB : kA;
            if (rank >= cumbase && rank < cumbase + s_local) {
                unsigned cum = cumbase;
                for (int b = 0; b < 256; b++) {
                    unsigned c = h[b0 + b];
                    if (rank < cum + c) { meta_u[s * 4 + t] = (unsigned)(b0 + b); meta_u[s * 4 + 2 + t] = rank - cum; break; }
                    cum += c;
                }
            }
        }
        __syncthreads();
    }
}

// ---------------- level-2 histogram (low 16 bits) restricted to selected prefixes ----------------
__global__ void hist2_kernel(const float* __restrict__ W1, int n1,
                             const float* __restrict__ W2, int n2,
                             const unsigned* __restrict__ meta_u, unsigned* __restrict__ hist2) {
    int tid = blockIdx.x * blockDim.x + threadIdx.x;
    int stride = gridDim.x * blockDim.x;
    for (int t = 0; t < 2; t++) {
        const float* W = t ? W2 : W1;
        int n = t ? n2 : n1;
        unsigned pa = meta_u[0 + t], pb = meta_u[4 + t];
        unsigned* hA = hist2 + (size_t)(t * 2 + 0) * 65536;
        unsigned* hB = hist2 + (size_t)(t * 2 + 1) * 65536;
        int n4 = n >> 2;
        for (int i = tid; i < n4; i += stride) {
            f32x4 w = ((const f32x4*)W)[i];
#pragma unroll
            for (int j = 0; j < 4; j++) {
                unsigned u = __float_as_uint(fabsf(w[j]));
                unsigned hi = u >> 16;
                if (hi == pa) atomicAdd(&hA[u & 0xffffu], 1u);
                if (hi == pb) atomicAdd(&hB[u & 0xffffu], 1u);
            }
        }
        for (int i = (n4 << 2) + tid; i < n; i += stride) {
            unsigned u = __float_as_uint(fabsf(W[i]));
            unsigned hi = u >> 16;
            if (hi == pa) atomicAdd(&hA[u & 0xffffu], 1u);
            if (hi == pb) atomicAdd(&hB[u & 0xffffu], 1u);
        }
    }
}

// ---------------- level-2 scan: exact order stats -> fp64 threshold + scale ----------------
__global__ void scan2_kernel(const unsigned* __restrict__ hist2, unsigned* __restrict__ meta_u,
                             const double* __restrict__ sums, const float* __restrict__ sparsity,
                             double* __restrict__ thr, int n1, int n2) {
    __shared__ unsigned partial[256];
    __shared__ unsigned basearr[256];
    __shared__ unsigned vb[2];
    float* meta_f = (float*)meta_u;
    for (int t = 0; t < 2; t++) {
        int n = t ? n2 : n1;
        for (int s = 0; s < 2; s++) {
            const unsigned* h = hist2 + (size_t)(t * 2 + s) * 65536;
            unsigned rank = meta_u[s * 4 + 2 + t];
            unsigned pfx = meta_u[s * 4 + t];
            int b0 = threadIdx.x * 256;
            unsigned s_local = 0;
            for (int b = 0; b < 256; b++) s_local += h[b0 + b];
            partial[threadIdx.x] = s_local;
            __syncthreads();
            if (threadIdx.x == 0) {
                unsigned run = 0;
                for (int i = 0; i < 256; i++) { unsigned tmp = partial[i]; basearr[i] = run; run += tmp; }
            }
            __syncthreads();
            unsigned cumbase = basearr[threadIdx.x];
            if (rank >= cumbase && rank < cumbase + s_local) {
                unsigned cum = cumbase;
                for (int b = 0; b < 256; b++) {
                    unsigned c = h[b0 + b];
                    if (rank < cum + c) { vb[s] = (pfx << 16) | (unsigned)(b0 + b); break; }
                    cum += c;
                }
            }
            __syncthreads();
        }
        if (threadIdx.x == 0) {
            double a = (double)__uint_as_float(vb[0]);
            double b = (double)__uint_as_float(vb[1]);
            double p = (double)(*sparsity) * (double)(n - 1);
            double tfr = p - floor(p);
            double th = (tfr >= 0.5) ? (b - (b - a) * (1.0 - tfr)) : (a + (b - a) * tfr);
            thr[t] = th;
            meta_f[8 + t] = (float)(sums[t] / (double)n);
        }
        __syncthreads();
    }
}

// ---------------- ternary quantize W -> bf16 {-1,0,+1} ----------------
__global__ void quantize_kernel(const float* __restrict__ W1, int n1,
                                const float* __restrict__ W2, int n2,
                                const double* __restrict__ thr,
                                unsigned short* __restrict__ wq1, unsigned short* __restrict__ wq2) {
    int tid = blockIdx.x * blockDim.x + threadIdx.x;
    int stride = gridDim.x * blockDim.x;
    for (int t = 0; t < 2; t++) {
        const float* W = t ? W2 : W1;
        unsigned short* O = t ? wq2 : wq1;
        int n = t ? n2 : n1;
        double th = thr[t];
        int n4 = n >> 2;
        for (int i = tid; i < n4; i += stride) {
            f32x4 w = ((const f32x4*)W)[i];
            ushort4v q;
#pragma unroll
            for (int j = 0; j < 4; j++) {
                float a = fabsf(w[j]);
                unsigned short v = 0;
                if ((double)a > th) v = (w[j] > 0.f) ? 0x3F80u : 0xBF80u;
                q[j] = v;
            }
            ((ushort4v*)O)[i] = q;
        }
        for (int i = (n4 << 2) + tid; i < n; i += stride) {
            float wv = W[i];
            float a = fabsf(wv);
            unsigned short v = 0;
            if ((double)a > th) v = (wv > 0.f) ? 0x3F80u : 0xBF80u;
            O[i] = v;
        }
    }
}

// ---------------- LN1 row stats (D=768, fp32 input), one wave per row ----------------
__global__ void ln1_stats_kernel(const float* __restrict__ x, float* __restrict__ mu,
                                 float* __restrict__ rs, int M) {
    int wave = threadIdx.x >> 6, lane = threadIdx.x & 63;
    int row = blockIdx.x * 4 + wave;
    if (row >= M) return;
    const float* xr = x + (size_t)row * D_DIM;
    float s = 0.f, s2 = 0.f;
#pragma unroll
    for (int i = 0; i < 3; i++) {
        f32x4 v = *(const f32x4*)&xr[lane * 4 + i * 256];
#pragma unroll
        for (int j = 0; j < 4; j++) { s += v[j]; s2 += v[j] * v[j]; }
    }
#pragma unroll
    for (int off = 32; off >= 1; off >>= 1) { s += __shfl_xor(s, off); s2 += __shfl_xor(s2, off); }
    if (lane == 0) {
        float m = s / (float)D_DIM;
        float var = s2 / (float)D_DIM - m * m;
        mu[row] = m;
        rs[row] = 1.f / sqrtf(var + 1e-5f);
    }
}

// ---------------- LN2 row stats (H=3072, bf16 input), one wave per row ----------------
__global__ void ln2_stats_kernel(const unsigned short* __restrict__ h1, float* __restrict__ mu,
                                 float* __restrict__ rs, int M) {
    int wave = threadIdx.x >> 6, lane = threadIdx.x & 63;
    int row = blockIdx.x * 4 + wave;
    if (row >= M) return;
    const unsigned short* hr = h1 + (size_t)row * H_DIM;
    float s = 0.f, s2 = 0.f;
#pragma unroll
    for (int i = 0; i < 6; i++) {
        ushort8 v = *(const ushort8*)&hr[lane * 8 + i * 512];
#pragma unroll
        for (int j = 0; j < 8; j++) { float f = bf2f(v[j]); s += f; s2 += f * f; }
    }
#pragma unroll
    for (int off = 32; off >= 1; off >>= 1) { s += __shfl_xor(s, off); s2 += __shfl_xor(s2, off); }
    if (lane == 0) {
        float m = s / (float)H_DIM;
        float var = s2 / (float)H_DIM - m * m;
        mu[row] = m;
        rs[row] = 1.f / sqrtf(var + 1e-5f);
    }
}

// ---------------- GEMM1: C = LN1(x) @ q1^T, epilogue: gelu(acc*scale + b1) -> bf16 h1 ----------------
__launch_bounds__(256)
__global__ void gemm1_kernel(const float* __restrict__ x, const float* __restrict__ mu1,
                             const float* __restrict__ rs1, const float* __restrict__ g1,
                             const float* __restrict__ bln1, const unsigned short* __restrict__ wq1,
                             const float* __restrict__ blin1, const float* __restrict__ meta_f,
                             unsigned short* __restrict__ h1) {
    __shared__ unsigned short As[128 * 32];
    __shared__ unsigned short Bs[128 * 32];
    const int m0 = blockIdx.y * 128, n0 = blockIdx.x * 128;
    const float scale = meta_f[8];
    const int t = threadIdx.x, lane = t & 63, wave = t >> 6;
    const int wm = (wave & 1) * 64, wn = (wave >> 1) * 64;
    const int l16 = lane & 15, l4 = lane >> 4, l8 = (lane >> 4) * 8;
    const int ak4 = (t & 7) * 4, ar0 = t >> 3;      // A staging: 8 thr/row, 4 rows
    const int bk8 = (t & 3) * 8, br0 = t >> 2;      // B staging: 4 thr/row, 2 rows

    f32x4 acc[4][4];
#pragma unroll
    for (int mi = 0; mi < 4; mi++)
#pragma unroll
        for (int ni = 0; ni < 4; ni++) acc[mi][ni] = (f32x4){0.f, 0.f, 0.f, 0.f};

    float amu[4], ars[4];
#pragma unroll
    for (int i = 0; i < 4; i++) { int gm = m0 + ar0 + 32 * i; amu[i] = mu1[gm]; ars[i] = rs1[gm]; }

    for (int k0 = 0; k0 < D_DIM; k0 += 32) {
#pragma unroll
        for (int i = 0; i < 4; i++) {
            int r = ar0 + 32 * i; int gm = m0 + r;
            f32x4 v = *(const f32x4*)&x[(size_t)gm * D_DIM + k0 + ak4];
            f32x4 g = *(const f32x4*)&g1[k0 + ak4];
            f32x4 bb = *(const f32x4*)&bln1[k0 + ak4];
            ushort4v pck;
#pragma unroll
            for (int j = 0; j < 4; j++) pck[j] = f2bf((v[j] - amu[i]) * ars[i] * g[j] + bb[j]);
            *(ushort4v*)&As[r * 32 + ak4] = pck;
        }
#pragma unroll
        for (int i = 0; i < 2; i++) {
            int r = br0 + 64 * i; int gn = n0 + r;
            ushort8 w = *(const ushort8*)&wq1[(size_t)gn * D_DIM + k0 + bk8];
            *(ushort8*)&Bs[r * 32 + bk8] = w;
        }
        __syncthreads();
        short8 af[4], bfr[4];
#pragma unroll
        for (int mi = 0; mi < 4; mi++) af[mi] = *(const short8*)&As[(wm + mi * 16 + l16) * 32 + l8];
#pragma unroll
        for (int ni = 0; ni < 4; ni++) bfr[ni] = *(const short8*)&Bs[(wn + ni * 16 + l16) * 32 + l8];
#pragma unroll
        for (int mi = 0; mi < 4; mi++)
#pragma unroll
            for (int ni = 0; ni < 4; ni++)
                acc[mi][ni] = __builtin_amdgcn_mfma_f32_16x16x32_bf16(af[mi], bfr[ni], acc[mi][ni], 0, 0, 0);
        __syncthreads();
    }
#pragma unroll
    for (int mi = 0; mi < 4; mi++)
#pragma unroll
        for (int ni = 0; ni < 4; ni++) {
            int col = n0 + wn + ni * 16 + l16;
            float bl = blin1[col];
#pragma unroll
            for (int j = 0; j < 4; j++) {
                int row = m0 + wm + mi * 16 + l4 * 4 + j;
                float v = acc[mi][ni][j] * scale + bl;
                float gel = 0.5f * v * (1.f + tanhf(0.7978845608028654f * (v + 0.044715f * v * v * v)));
                h1[(size_t)row * H_DIM + col] = f2bf(gel);
            }
        }
}

// ---------------- GEMM2: out = LN2(h1) @ q2^T * scale2 + b2 (fp32 out) ----------------
__launch_bounds__(256)
__global__ void gemm2_kernel(const unsigned short* __restrict__ h1, const float* __restrict__ mu2,
                             const float* __restrict__ rs2, const float* __restrict__ g2,
                             const float* __restrict__ bln2, const unsigned short* __restrict__ wq2,
                             const float* __restrict__ blin2, const float* __restrict__ meta_f,
                             float* __restrict__ out) {
    __shared__ unsigned short As[128 * 32];
    __shared__ unsigned short Bs[128 * 32];
    const int m0 = blockIdx.y * 128, n0 = blockIdx.x * 128;
    const float scale = meta_f[9];
    const int t = threadIdx.x, lane = t & 63, wave = t >> 6;
    const int wm = (wave & 1) * 64, wn = (wave >> 1) * 64;
    const int l16 = lane & 15, l4 = lane >> 4, l8 = (lane >> 4) * 8;
    const int ak8 = (t & 3) * 8, ar0 = t >> 2;      // A staging: 4 thr/row, 2 rows
    const int bk8 = (t & 3) * 8, br0 = t >> 2;      // B staging: 4 thr/row, 2 rows

    f32x4 acc[4][4];
#pragma unroll
    for (int mi = 0; mi < 4; mi++)
#pragma unroll
        for (int ni = 0; ni < 4; ni++) acc[mi][ni] = (f32x4){0.f, 0.f, 0.f, 0.f};

    float amu[2], ars[2];
#pragma unroll
    for (int i = 0; i < 2; i++) { int gm = m0 + ar0 + 64 * i; amu[i] = mu2[gm]; ars[i] = rs2[gm]; }

    for (int k0 = 0; k0 < H_DIM; k0 += 32) {
#pragma unroll
        for (int i = 0; i < 2; i++) {
            int r = ar0 + 64 * i; int gm = m0 + r;
            ushort8 hv = *(const ushort8*)&h1[(size_t)gm * H_DIM + k0 + ak8];
            f32x4 ga = *(const f32x4*)&g2[k0 + ak8];
            f32x4 gb = *(const f32x4*)&g2[k0 + ak8 + 4];
            f32x4 ba = *(const f32x4*)&bln2[k0 + ak8];
            f32x4 bb = *(const f32x4*)&bln2[k0 + ak8 + 4];
            ushort8 pck;
#pragma unroll
            for (int j = 0; j < 4; j++) {
                float f = bf2f(hv[j]);
                pck[j] = f2bf((f - amu[i]) * ars[i] * ga[j] + ba[j]);
            }
#pragma unroll
            for (int j = 0; j < 4; j++) {
                float f = bf2f(hv[4 + j]);
                pck[4 + j] = f2bf((f - amu[i]) * ars[i] * gb[j] + bb[j]);
            }
            *(ushort8*)&As[r * 32 + ak8] = pck;
        }
#pragma unroll
        for (int i = 0; i < 2; i++) {
            int r = br0 + 64 * i; int gn = n0 + r;
            ushort8 w = *(const ushort8*)&wq2[(size_t)gn * H_DIM + k0 + bk8];
            *(ushort8*)&Bs[r * 32 + bk8] = w;
        }
        __syncthreads();
        short8 af[4], bfr[4];
#pragma unroll
        for (int mi = 0; mi < 4; mi++) af[mi] = *(const short8*)&As[(wm + mi * 16 + l16) * 32 + l8];
#pragma unroll
        for (int ni = 0; ni < 4; ni++) bfr[ni] = *(const short8*)&Bs[(wn + ni * 16 + l16) * 32 + l8];
#pragma unroll
        for (int mi = 0; mi < 4; mi++)
#pragma unroll
            for (int ni = 0; ni < 4; ni++)
                acc[mi][ni] = __builtin_amdgcn_mfma_f32_16x16x32_bf16(af[mi], bfr[ni], acc[mi][ni], 0, 0, 0);
        __syncthreads();
    }
#pragma unroll
    for (int mi = 0; mi < 4; mi++)
#pragma unroll
        for (int ni = 0; ni < 4; ni++) {
            int col = n0 + wn + ni * 16 + l16;
            float bl = blin2[col];
#pragma unroll
            for (int j = 0; j < 4; j++) {
                int row = m0 + wm + mi * 16 + l4 * 4 + j;
                out[(size_t)row * D_DIM + col] = acc[mi][ni][j] * scale + bl;
            }
        }
}

extern "C" void kernel_launch(void* const* d_in, const int* in_sizes, int n_in,
                              void* d_out, int out_size, void* d_ws, size_t ws_size,
                              hipStream_t stream) {
    const float* x    = (const float*)d_in[0];
    const float* ln1g = (const float*)d_in[1];
    const float* ln1b = (const float*)d_in[2];
    const float* W1   = (const float*)d_in[3];
    const float* b1   = (const float*)d_in[4];
    const float* ln2g = (const float*)d_in[5];
    const float* ln2b = (const float*)d_in[6];
    const float* W2   = (const float*)d_in[7];
    const float* b2   = (const float*)d_in[8];
    const float* sp   = (const float*)d_in[9];
    const int n1 = in_sizes[3], n2 = in_sizes[7];
    const int M = in_sizes[0] / D_DIM;

    char* ws = (char*)d_ws;
    unsigned* hist1 = (unsigned*)(ws + HIST1_OFF);
    unsigned* hist2 = (unsigned*)(ws + HIST2_OFF);
    double*   sums  = (double*)(ws + SUM_OFF);
    double*   thr   = (double*)(ws + THR_OFF);
    unsigned* meta_u = (unsigned*)(ws + META_OFF);
    float*    meta_f = (float*)(ws + META_OFF);
    float* mu1 = (float*)(ws + MU1_OFF);
    float* rs1 = (float*)(ws + RS1_OFF);
    float* mu2 = (float*)(ws + MU2_OFF);
    float* rs2 = (float*)(ws + RS2_OFF);
    unsigned short* wq1 = (unsigned short*)(ws + WQ1_OFF);
    unsigned short* wq2 = (unsigned short*)(ws + WQ2_OFF);
    unsigned short* h1  = (unsigned short*)(ws + H1_OFF);

    hipMemsetAsync(d_ws, 0, ZERO_BYTES, stream);
    hist_abs_kernel<<<2048, 256, 0, stream>>>(W1, n1, W2, n2, hist1, sums);
    scan1_kernel<<<1, 256, 0, stream>>>(hist1, meta_u, sp, n1, n2);
    hist2_kernel<<<2048, 256, 0, stream>>>(W1, n1, W2, n2, meta_u, hist2);
    scan2_kernel<<<1, 256, 0, stream>>>(hist2, meta_u, sums, sp, thr, n1, n2);
    quantize_kernel<<<2048, 256, 0, stream>>>(W1, n1, W2, n2, thr, wq1, wq2);
    ln1_stats_kernel<<<M / 4, 256, 0, stream>>>(x, mu1, rs1, M);
    gemm1_kernel<<<dim3(H_DIM / 128, M / 128), 256, 0, stream>>>(x, mu1, rs1, ln1g, ln1b, wq1, b1, meta_f, h1);
    ln2_stats_kernel<<<M / 4, 256, 0, stream>>>(h1, mu2, rs2, M);
    gemm2_kernel<<<dim3(D_DIM / 128, M / 128), 256, 0, stream>>>(h1, mu2, rs2, ln2g, ln2b, wq2, b2, meta_f, (float*)d_out);
}

// Round 5
// 1351.592 us; speedup vs baseline: 1.6395x; 1.6395x over previous
//
#include <hip/hip_runtime.h>
#include <math.h>

using f32x4    = __attribute__((ext_vector_type(4))) float;
using short8   = __attribute__((ext_vector_type(8))) short;
using ushort8  = __attribute__((ext_vector_type(8))) unsigned short;
using ushort4v = __attribute__((ext_vector_type(4))) unsigned short;

#define D_DIM 768
#define H_DIM 3072

// level-1: top 14 bits of |w| bit pattern (16384 buckets, LDS-privatized)
// level-2: low 18 bits (262144 buckets, global, contention-free)
#define L1_BITS 14
#define L1_SIZE 16384
#define L2_SIZE 262144
#define L2_MASK 0x3FFFFu

// ---------------- ws layout (bytes) ----------------
static const size_t HIST1_OFF = 0;                        // 2*16384*4 = 131072
static const size_t HIST2_OFF = 131072;                   // 4*262144*4 = 4194304 -> end 4325376
static const size_t SUM_OFF   = 4325376;                  // double[2]
static const size_t THR_OFF   = 4325392;                  // double[2]
static const size_t META_OFF  = 4325408;                  // u32[16]
static const size_t ZERO_BYTES= 4325472;
static const size_t MU1_OFF   = 4456448;                  // f32[32768]
static const size_t RS1_OFF   = MU1_OFF + 131072;
static const size_t MU2_OFF   = RS1_OFF + 131072;
static const size_t RS2_OFF   = MU2_OFF + 131072;
static const size_t WQ1_OFF   = 5242880;                  // bf16[3072*768] = 4718592
static const size_t WQ2_OFF   = WQ1_OFF + 4718592;        // end 14680064
static const size_t H1_OFF    = 16777216;                 // bf16[32768*3072] = 201326592

// meta (u32 view): [0..1] pfxA[t], [2..3] remA[t], [4..5] pfxB[t], [6..7] remB[t]
// meta (f32 view): [8..9] scale[t]

__device__ __forceinline__ unsigned short f2bf(float f) {
    unsigned u = __float_as_uint(f);
    u += 0x7fffu + ((u >> 16) & 1u);
    return (unsigned short)(u >> 16);
}
__device__ __forceinline__ float bf2f(unsigned short s) {
    return __uint_as_float(((unsigned)s) << 16);
}

// ---------------- LDS-privatized 14-bit histogram of |w| + fp64 abs-sum ----------------
// blockIdx.y selects tensor. Merge only nonzero buckets to global.
__global__ void hist_abs_kernel(const float* __restrict__ W1, int n1,
                                const float* __restrict__ W2, int n2,
                                unsigned* __restrict__ hist, double* __restrict__ sums) {
    __shared__ unsigned lh[L1_SIZE];
    const int t = blockIdx.y;
    const float* W = t ? W2 : W1;
    const int n = t ? n2 : n1;
    unsigned* hg = hist + (size_t)t * L1_SIZE;

    for (int i = threadIdx.x; i < L1_SIZE; i += 256) lh[i] = 0;
    __syncthreads();

    int tid = blockIdx.x * blockDim.x + threadIdx.x;
    int stride = gridDim.x * blockDim.x;
    double local = 0.0;
    int n4 = n >> 2;
    for (int i = tid; i < n4; i += stride) {
        f32x4 w = ((const f32x4*)W)[i];
#pragma unroll
        for (int j = 0; j < 4; j++) {
            float a = fabsf(w[j]);
            local += (double)a;
            atomicAdd(&lh[__float_as_uint(a) >> (32 - L1_BITS)], 1u);
        }
    }
    for (int i = (n4 << 2) + tid; i < n; i += stride) {
        float a = fabsf(W[i]);
        local += (double)a;
        atomicAdd(&lh[__float_as_uint(a) >> (32 - L1_BITS)], 1u);
    }
    __syncthreads();
    for (int i = threadIdx.x; i < L1_SIZE; i += 256) {
        unsigned c = lh[i];
        if (c) atomicAdd(&hg[i], c);
    }
#pragma unroll
    for (int off = 32; off >= 1; off >>= 1) local += __shfl_down(local, off);
    if ((threadIdx.x & 63) == 0) atomicAdd(&sums[t], local);
}

// ---------------- level-1 scan: find 14-bit prefix bucket for ranks k and k+1 ----------------
__global__ void scan1_kernel(const unsigned* __restrict__ hist, unsigned* __restrict__ meta_u,
                             const float* __restrict__ sparsity, int n1, int n2) {
    __shared__ unsigned partial[256];
    __shared__ unsigned basearr[256];
    for (int t = 0; t < 2; t++) {
        const unsigned* h = hist + (size_t)t * L1_SIZE;
        int n = t ? n2 : n1;
        double p = (double)(*sparsity) * (double)(n - 1);
        unsigned kA = (unsigned)floor(p);
        unsigned kB = kA + 1; if (kB > (unsigned)(n - 1)) kB = (unsigned)(n - 1);
        int b0 = threadIdx.x * (L1_SIZE / 256);
        unsigned s_local = 0;
        for (int b = 0; b < L1_SIZE / 256; b++) s_local += h[b0 + b];
        partial[threadIdx.x] = s_local;
        __syncthreads();
        if (threadIdx.x == 0) {
            unsigned run = 0;
            for (int i = 0; i < 256; i++) { unsigned tmp = partial[i]; basearr[i] = run; run += tmp; }
        }
        __syncthreads();
        unsigned cumbase = basearr[threadIdx.x];
        for (int s = 0; s < 2; s++) {
            unsigned rank = s ? kB : kA;
            if (rank >= cumbase && rank < cumbase + s_local) {
                unsigned cum = cumbase;
                for (int b = 0; b < L1_SIZE / 256; b++) {
                    unsigned c = h[b0 + b];
                    if (rank < cum + c) { meta_u[s * 4 + t] = (unsigned)(b0 + b); meta_u[s * 4 + 2 + t] = rank - cum; break; }
                    cum += c;
                }
            }
        }
        __syncthreads();
    }
}

// ---------------- level-2 histogram (low 18 bits) restricted to selected prefixes ----------------
__global__ void hist2_kernel(const float* __restrict__ W1, int n1,
                             const float* __restrict__ W2, int n2,
                             const unsigned* __restrict__ meta_u, unsigned* __restrict__ hist2) {
    int tid = blockIdx.x * blockDim.x + threadIdx.x;
    int stride = gridDim.x * blockDim.x;
    for (int t = 0; t < 2; t++) {
        const float* W = t ? W2 : W1;
        int n = t ? n2 : n1;
        unsigned pa = meta_u[0 + t], pb = meta_u[4 + t];
        unsigned* hA = hist2 + (size_t)(t * 2 + 0) * L2_SIZE;
        unsigned* hB = hist2 + (size_t)(t * 2 + 1) * L2_SIZE;
        int n4 = n >> 2;
        for (int i = tid; i < n4; i += stride) {
            f32x4 w = ((const f32x4*)W)[i];
#pragma unroll
            for (int j = 0; j < 4; j++) {
                unsigned u = __float_as_uint(fabsf(w[j]));
                unsigned hi = u >> (32 - L1_BITS);
                if (hi == pa) atomicAdd(&hA[u & L2_MASK], 1u);
                if (hi == pb) atomicAdd(&hB[u & L2_MASK], 1u);
            }
        }
        for (int i = (n4 << 2) + tid; i < n; i += stride) {
            unsigned u = __float_as_uint(fabsf(W[i]));
            unsigned hi = u >> (32 - L1_BITS);
            if (hi == pa) atomicAdd(&hA[u & L2_MASK], 1u);
            if (hi == pb) atomicAdd(&hB[u & L2_MASK], 1u);
        }
    }
}

// ---------------- level-2 scan: exact order stats -> fp64 threshold + scale ----------------
__global__ void scan2_kernel(const unsigned* __restrict__ hist2, unsigned* __restrict__ meta_u,
                             const double* __restrict__ sums, const float* __restrict__ sparsity,
                             double* __restrict__ thr, int n1, int n2) {
    __shared__ unsigned partial[256];
    __shared__ unsigned basearr[256];
    __shared__ unsigned vb[2];
    float* meta_f = (float*)meta_u;
    for (int t = 0; t < 2; t++) {
        int n = t ? n2 : n1;
        for (int s = 0; s < 2; s++) {
            const unsigned* h = hist2 + (size_t)(t * 2 + s) * L2_SIZE;
            unsigned rank = meta_u[s * 4 + 2 + t];
            unsigned pfx = meta_u[s * 4 + t];
            int b0 = threadIdx.x * (L2_SIZE / 256);
            unsigned s_local = 0;
            for (int b = 0; b < L2_SIZE / 256; b++) s_local += h[b0 + b];
            partial[threadIdx.x] = s_local;
            __syncthreads();
            if (threadIdx.x == 0) {
                unsigned run = 0;
                for (int i = 0; i < 256; i++) { unsigned tmp = partial[i]; basearr[i] = run; run += tmp; }
            }
            __syncthreads();
            unsigned cumbase = basearr[threadIdx.x];
            if (rank >= cumbase && rank < cumbase + s_local) {
                unsigned cum = cumbase;
                for (int b = 0; b < L2_SIZE / 256; b++) {
                    unsigned c = h[b0 + b];
                    if (rank < cum + c) { vb[s] = (pfx << (32 - L1_BITS)) | (unsigned)(b0 + b); break; }
                    cum += c;
                }
            }
            __syncthreads();
        }
        if (threadIdx.x == 0) {
            double a = (double)__uint_as_float(vb[0]);
            double b = (double)__uint_as_float(vb[1]);
            double p = (double)(*sparsity) * (double)(n - 1);
            double tfr = p - floor(p);
            double th = (tfr >= 0.5) ? (b - (b - a) * (1.0 - tfr)) : (a + (b - a) * tfr);
            thr[t] = th;
            meta_f[8 + t] = (float)(sums[t] / (double)n);
        }
        __syncthreads();
    }
}

// ---------------- ternary quantize W -> bf16 {-1,0,+1} ----------------
__global__ void quantize_kernel(const float* __restrict__ W1, int n1,
                                const float* __restrict__ W2, int n2,
                                const double* __restrict__ thr,
                                unsigned short* __restrict__ wq1, unsigned short* __restrict__ wq2) {
    int tid = blockIdx.x * blockDim.x + threadIdx.x;
    int stride = gridDim.x * blockDim.x;
    for (int t = 0; t < 2; t++) {
        const float* W = t ? W2 : W1;
        unsigned short* O = t ? wq2 : wq1;
        int n = t ? n2 : n1;
        double th = thr[t];
        int n4 = n >> 2;
        for (int i = tid; i < n4; i += stride) {
            f32x4 w = ((const f32x4*)W)[i];
            ushort4v q;
#pragma unroll
            for (int j = 0; j < 4; j++) {
                float a = fabsf(w[j]);
                unsigned short v = 0;
                if ((double)a > th) v = (w[j] > 0.f) ? 0x3F80u : 0xBF80u;
                q[j] = v;
            }
            ((ushort4v*)O)[i] = q;
        }
        for (int i = (n4 << 2) + tid; i < n; i += stride) {
            float wv = W[i];
            float a = fabsf(wv);
            unsigned short v = 0;
            if ((double)a > th) v = (wv > 0.f) ? 0x3F80u : 0xBF80u;
            O[i] = v;
        }
    }
}

// ---------------- LN1 row stats (D=768, fp32 input), one wave per row ----------------
__global__ void ln1_stats_kernel(const float* __restrict__ x, float* __restrict__ mu,
                                 float* __restrict__ rs, int M) {
    int wave = threadIdx.x >> 6, lane = threadIdx.x & 63;
    int row = blockIdx.x * 4 + wave;
    if (row >= M) return;
    const float* xr = x + (size_t)row * D_DIM;
    float s = 0.f, s2 = 0.f;
#pragma unroll
    for (int i = 0; i < 3; i++) {
        f32x4 v = *(const f32x4*)&xr[lane * 4 + i * 256];
#pragma unroll
        for (int j = 0; j < 4; j++) { s += v[j]; s2 += v[j] * v[j]; }
    }
#pragma unroll
    for (int off = 32; off >= 1; off >>= 1) { s += __shfl_xor(s, off); s2 += __shfl_xor(s2, off); }
    if (lane == 0) {
        float m = s / (float)D_DIM;
        float var = s2 / (float)D_DIM - m * m;
        mu[row] = m;
        rs[row] = 1.f / sqrtf(var + 1e-5f);
    }
}

// ---------------- LN2 row stats (H=3072, bf16 input), one wave per row ----------------
__global__ void ln2_stats_kernel(const unsigned short* __restrict__ h1, float* __restrict__ mu,
                                 float* __restrict__ rs, int M) {
    int wave = threadIdx.x >> 6, lane = threadIdx.x & 63;
    int row = blockIdx.x * 4 + wave;
    if (row >= M) return;
    const unsigned short* hr = h1 + (size_t)row * H_DIM;
    float s = 0.f, s2 = 0.f;
#pragma unroll
    for (int i = 0; i < 6; i++) {
        ushort8 v = *(const ushort8*)&hr[lane * 8 + i * 512];
#pragma unroll
        for (int j = 0; j < 8; j++) { float f = bf2f(v[j]); s += f; s2 += f * f; }
    }
#pragma unroll
    for (int off = 32; off >= 1; off >>= 1) { s += __shfl_xor(s, off); s2 += __shfl_xor(s2, off); }
    if (lane == 0) {
        float m = s / (float)H_DIM;
        float var = s2 / (float)H_DIM - m * m;
        mu[row] = m;
        rs[row] = 1.f / sqrtf(var + 1e-5f);
    }
}

// ---------------- GEMM1: C = LN1(x) @ q1^T, epilogue: gelu(acc*scale + b1) -> bf16 h1 ----------------
__launch_bounds__(256)
__global__ void gemm1_kernel(const float* __restrict__ x, const float* __restrict__ mu1,
                             const float* __restrict__ rs1, const float* __restrict__ g1,
                             const float* __restrict__ bln1, const unsigned short* __restrict__ wq1,
                             const float* __restrict__ blin1, const float* __restrict__ meta_f,
                             unsigned short* __restrict__ h1) {
    __shared__ unsigned short As[128 * 32];
    __shared__ unsigned short Bs[128 * 32];
    const int m0 = blockIdx.y * 128, n0 = blockIdx.x * 128;
    const float scale = meta_f[8];
    const int t = threadIdx.x, lane = t & 63, wave = t >> 6;
    const int wm = (wave & 1) * 64, wn = (wave >> 1) * 64;
    const int l16 = lane & 15, l4 = lane >> 4, l8 = (lane >> 4) * 8;
    const int ak4 = (t & 7) * 4, ar0 = t >> 3;      // A staging: 8 thr/row, 4 rows
    const int bk8 = (t & 3) * 8, br0 = t >> 2;      // B staging: 4 thr/row, 2 rows

    f32x4 acc[4][4];
#pragma unroll
    for (int mi = 0; mi < 4; mi++)
#pragma unroll
        for (int ni = 0; ni < 4; ni++) acc[mi][ni] = (f32x4){0.f, 0.f, 0.f, 0.f};

    float amu[4], ars[4];
#pragma unroll
    for (int i = 0; i < 4; i++) { int gm = m0 + ar0 + 32 * i; amu[i] = mu1[gm]; ars[i] = rs1[gm]; }

    for (int k0 = 0; k0 < D_DIM; k0 += 32) {
#pragma unroll
        for (int i = 0; i < 4; i++) {
            int r = ar0 + 32 * i; int gm = m0 + r;
            f32x4 v = *(const f32x4*)&x[(size_t)gm * D_DIM + k0 + ak4];
            f32x4 g = *(const f32x4*)&g1[k0 + ak4];
            f32x4 bb = *(const f32x4*)&bln1[k0 + ak4];
            ushort4v pck;
#pragma unroll
            for (int j = 0; j < 4; j++) pck[j] = f2bf((v[j] - amu[i]) * ars[i] * g[j] + bb[j]);
            *(ushort4v*)&As[r * 32 + ak4] = pck;
        }
#pragma unroll
        for (int i = 0; i < 2; i++) {
            int r = br0 + 64 * i; int gn = n0 + r;
            ushort8 w = *(const ushort8*)&wq1[(size_t)gn * D_DIM + k0 + bk8];
            *(ushort8*)&Bs[r * 32 + bk8] = w;
        }
        __syncthreads();
        short8 af[4], bfr[4];
#pragma unroll
        for (int mi = 0; mi < 4; mi++) af[mi] = *(const short8*)&As[(wm + mi * 16 + l16) * 32 + l8];
#pragma unroll
        for (int ni = 0; ni < 4; ni++) bfr[ni] = *(const short8*)&Bs[(wn + ni * 16 + l16) * 32 + l8];
#pragma unroll
        for (int mi = 0; mi < 4; mi++)
#pragma unroll
            for (int ni = 0; ni < 4; ni++)
                acc[mi][ni] = __builtin_amdgcn_mfma_f32_16x16x32_bf16(af[mi], bfr[ni], acc[mi][ni], 0, 0, 0);
        __syncthreads();
    }
#pragma unroll
    for (int mi = 0; mi < 4; mi++)
#pragma unroll
        for (int ni = 0; ni < 4; ni++) {
            int col = n0 + wn + ni * 16 + l16;
            float bl = blin1[col];
#pragma unroll
            for (int j = 0; j < 4; j++) {
                int row = m0 + wm + mi * 16 + l4 * 4 + j;
                float v = acc[mi][ni][j] * scale + bl;
                float gel = 0.5f * v * (1.f + tanhf(0.7978845608028654f * (v + 0.044715f * v * v * v)));
                h1[(size_t)row * H_DIM + col] = f2bf(gel);
            }
        }
}

// ---------------- GEMM2: out = LN2(h1) @ q2^T * scale2 + b2 (fp32 out) ----------------
__launch_bounds__(256)
__global__ void gemm2_kernel(const unsigned short* __restrict__ h1, const float* __restrict__ mu2,
                             const float* __restrict__ rs2, const float* __restrict__ g2,
                             const float* __restrict__ bln2, const unsigned short* __restrict__ wq2,
                             const float* __restrict__ blin2, const float* __restrict__ meta_f,
                             float* __restrict__ out) {
    __shared__ unsigned short As[128 * 32];
    __shared__ unsigned short Bs[128 * 32];
    const int m0 = blockIdx.y * 128, n0 = blockIdx.x * 128;
    const float scale = meta_f[9];
    const int t = threadIdx.x, lane = t & 63, wave = t >> 6;
    const int wm = (wave & 1) * 64, wn = (wave >> 1) * 64;
    const int l16 = lane & 15, l4 = lane >> 4, l8 = (lane >> 4) * 8;
    const int ak8 = (t & 3) * 8, ar0 = t >> 2;      // A staging: 4 thr/row, 2 rows
    const int bk8 = (t & 3) * 8, br0 = t >> 2;      // B staging: 4 thr/row, 2 rows

    f32x4 acc[4][4];
#pragma unroll
    for (int mi = 0; mi < 4; mi++)
#pragma unroll
        for (int ni = 0; ni < 4; ni++) acc[mi][ni] = (f32x4){0.f, 0.f, 0.f, 0.f};

    float amu[2], ars[2];
#pragma unroll
    for (int i = 0; i < 2; i++) { int gm = m0 + ar0 + 64 * i; amu[i] = mu2[gm]; ars[i] = rs2[gm]; }

    for (int k0 = 0; k0 < H_DIM; k0 += 32) {
#pragma unroll
        for (int i = 0; i < 2; i++) {
            int r = ar0 + 64 * i; int gm = m0 + r;
            ushort8 hv = *(const ushort8*)&h1[(size_t)gm * H_DIM + k0 + ak8];
            f32x4 ga = *(const f32x4*)&g2[k0 + ak8];
            f32x4 gb = *(const f32x4*)&g2[k0 + ak8 + 4];
            f32x4 ba = *(const f32x4*)&bln2[k0 + ak8];
            f32x4 bb = *(const f32x4*)&bln2[k0 + ak8 + 4];
            ushort8 pck;
#pragma unroll
            for (int j = 0; j < 4; j++) {
                float f = bf2f(hv[j]);
                pck[j] = f2bf((f - amu[i]) * ars[i] * ga[j] + ba[j]);
            }
#pragma unroll
            for (int j = 0; j < 4; j++) {
                float f = bf2f(hv[4 + j]);
                pck[4 + j] = f2bf((f - amu[i]) * ars[i] * gb[j] + bb[j]);
            }
            *(ushort8*)&As[r * 32 + ak8] = pck;
        }
#pragma unroll
        for (int i = 0; i < 2; i++) {
            int r = br0 + 64 * i; int gn = n0 + r;
            ushort8 w = *(const ushort8*)&wq2[(size_t)gn * H_DIM + k0 + bk8];
            *(ushort8*)&Bs[r * 32 + bk8] = w;
        }
        __syncthreads();
        short8 af[4], bfr[4];
#pragma unroll
        for (int mi = 0; mi < 4; mi++) af[mi] = *(const short8*)&As[(wm + mi * 16 + l16) * 32 + l8];
#pragma unroll
        for (int ni = 0; ni < 4; ni++) bfr[ni] = *(const short8*)&Bs[(wn + ni * 16 + l16) * 32 + l8];
#pragma unroll
        for (int mi = 0; mi < 4; mi++)
#pragma unroll
            for (int ni = 0; ni < 4; ni++)
                acc[mi][ni] = __builtin_amdgcn_mfma_f32_16x16x32_bf16(af[mi], bfr[ni], acc[mi][ni], 0, 0, 0);
        __syncthreads();
    }
#pragma unroll
    for (int mi = 0; mi < 4; mi++)
#pragma unroll
        for (int ni = 0; ni < 4; ni++) {
            int col = n0 + wn + ni * 16 + l16;
            float bl = blin2[col];
#pragma unroll
            for (int j = 0; j < 4; j++) {
                int row = m0 + wm + mi * 16 + l4 * 4 + j;
                out[(size_t)row * D_DIM + col] = acc[mi][ni][j] * scale + bl;
            }
        }
}

extern "C" void kernel_launch(void* const* d_in, const int* in_sizes, int n_in,
                              void* d_out, int out_size, void* d_ws, size_t ws_size,
                              hipStream_t stream) {
    const float* x    = (const float*)d_in[0];
    const float* ln1g = (const float*)d_in[1];
    const float* ln1b = (const float*)d_in[2];
    const float* W1   = (const float*)d_in[3];
    const float* b1   = (const float*)d_in[4];
    const float* ln2g = (const float*)d_in[5];
    const float* ln2b = (const float*)d_in[6];
    const float* W2   = (const float*)d_in[7];
    const float* b2   = (const float*)d_in[8];
    const float* sp   = (const float*)d_in[9];
    const int n1 = in_sizes[3], n2 = in_sizes[7];
    const int M = in_sizes[0] / D_DIM;

    char* ws = (char*)d_ws;
    unsigned* hist1 = (unsigned*)(ws + HIST1_OFF);
    unsigned* hist2 = (unsigned*)(ws + HIST2_OFF);
    double*   sums  = (double*)(ws + SUM_OFF);
    double*   thr   = (double*)(ws + THR_OFF);
    unsigned* meta_u = (unsigned*)(ws + META_OFF);
    float*    meta_f = (float*)(ws + META_OFF);
    float* mu1 = (float*)(ws + MU1_OFF);
    float* rs1 = (float*)(ws + RS1_OFF);
    float* mu2 = (float*)(ws + MU2_OFF);
    float* rs2 = (float*)(ws + RS2_OFF);
    unsigned short* wq1 = (unsigned short*)(ws + WQ1_OFF);
    unsigned short* wq2 = (unsigned short*)(ws + WQ2_OFF);
    unsigned short* h1  = (unsigned short*)(ws + H1_OFF);

    hipMemsetAsync(d_ws, 0, ZERO_BYTES, stream);
    hist_abs_kernel<<<dim3(512, 2), 256, 0, stream>>>(W1, n1, W2, n2, hist1, sums);
    scan1_kernel<<<1, 256, 0, stream>>>(hist1, meta_u, sp, n1, n2);
    hist2_kernel<<<2048, 256, 0, stream>>>(W1, n1, W2, n2, meta_u, hist2);
    scan2_kernel<<<1, 256, 0, stream>>>(hist2, meta_u, sums, sp, thr, n1, n2);
    quantize_kernel<<<2048, 256, 0, stream>>>(W1, n1, W2, n2, thr, wq1, wq2);
    ln1_stats_kernel<<<M / 4, 256, 0, stream>>>(x, mu1, rs1, M);
    gemm1_kernel<<<dim3(H_DIM / 128, M / 128), 256, 0, stream>>>(x, mu1, rs1, ln1g, ln1b, wq1, b1, meta_f, h1);
    ln2_stats_kernel<<<M / 4, 256, 0, stream>>>(h1, mu2, rs2, M);
    gemm2_kernel<<<dim3(D_DIM / 128, M / 128), 256, 0, stream>>>(h1, mu2, rs2, ln2g, ln2b, wq2, b2, meta_f, (float*)d_out);
}

// Round 6
// 1067.563 us; speedup vs baseline: 2.0757x; 1.2661x over previous
//
#include <hip/hip_runtime.h>
#include <math.h>

using f32x4    = __attribute__((ext_vector_type(4))) float;
using short8   = __attribute__((ext_vector_type(8))) short;
using ushort8  = __attribute__((ext_vector_type(8))) unsigned short;
using ushort4v = __attribute__((ext_vector_type(4))) unsigned short;

#define D_DIM 768
#define H_DIM 3072

// level-1: top 14 bits of |w| bit pattern (16384 buckets, LDS-privatized)
// level-2: low 18 bits (262144 buckets, global, contention-free)
#define L1_BITS 14
#define L1_SIZE 16384
#define L2_SIZE 262144
#define L2_MASK 0x3FFFFu

// ---------------- ws layout (bytes) ----------------
static const size_t HIST1_OFF = 0;                        // 2*16384*4 = 131072
static const size_t HIST2_OFF = 131072;                   // 4*262144*4 = 4194304 -> end 4325376
static const size_t SUM_OFF   = 4325376;                  // double[2]
static const size_t THR_OFF   = 4325392;                  // double[2]
static const size_t META_OFF  = 4325408;                  // u32[16]
static const size_t ZERO_BYTES= 4325472;
static const size_t WQ1_OFF   = 5242880;                  // bf16[3072*768] = 4718592
static const size_t WQ2_OFF   = WQ1_OFF + 4718592;        // end 14680064
static const size_t H1_OFF    = 16777216;                 // bf16[32768*3072] = 201326592
// xn (bf16 LN1(x), 48 MB) lives in d_out until gemm2 overwrites it (stream-ordered).

// meta (u32 view): [0..1] pfxA[t], [2..3] remA[t], [4..5] pfxB[t], [6..7] remB[t]
// meta (f32 view): [8..9] scale[t]

__device__ __forceinline__ unsigned short f2bf(float f) {
    unsigned u = __float_as_uint(f);
    u += 0x7fffu + ((u >> 16) & 1u);
    return (unsigned short)(u >> 16);
}
__device__ __forceinline__ float bf2f(unsigned short s) {
    return __uint_as_float(((unsigned)s) << 16);
}

// async global->LDS, 16 B per lane. LDS dest must be wave-uniform base + lane*16.
__device__ __forceinline__ void gload16(const unsigned short* g, unsigned short* l) {
    __builtin_amdgcn_global_load_lds(
        (const __attribute__((address_space(1))) unsigned int*)g,
        (__attribute__((address_space(3))) unsigned int*)l, 16, 0, 0);
}

// ---------------- LDS-privatized 14-bit histogram of |w| + fp64 abs-sum ----------------
__global__ void hist_abs_kernel(const float* __restrict__ W1, int n1,
                                const float* __restrict__ W2, int n2,
                                unsigned* __restrict__ hist, double* __restrict__ sums) {
    __shared__ unsigned lh[L1_SIZE];
    const int t = blockIdx.y;
    const float* W = t ? W2 : W1;
    const int n = t ? n2 : n1;
    unsigned* hg = hist + (size_t)t * L1_SIZE;

    for (int i = threadIdx.x; i < L1_SIZE; i += 256) lh[i] = 0;
    __syncthreads();

    int tid = blockIdx.x * blockDim.x + threadIdx.x;
    int stride = gridDim.x * blockDim.x;
    double local = 0.0;
    int n4 = n >> 2;
    for (int i = tid; i < n4; i += stride) {
        f32x4 w = ((const f32x4*)W)[i];
#pragma unroll
        for (int j = 0; j < 4; j++) {
            float a = fabsf(w[j]);
            local += (double)a;
            atomicAdd(&lh[__float_as_uint(a) >> (32 - L1_BITS)], 1u);
        }
    }
    for (int i = (n4 << 2) + tid; i < n; i += stride) {
        float a = fabsf(W[i]);
        local += (double)a;
        atomicAdd(&lh[__float_as_uint(a) >> (32 - L1_BITS)], 1u);
    }
    __syncthreads();
    for (int i = threadIdx.x; i < L1_SIZE; i += 256) {
        unsigned c = lh[i];
        if (c) atomicAdd(&hg[i], c);
    }
#pragma unroll
    for (int off = 32; off >= 1; off >>= 1) local += __shfl_down(local, off);
    if ((threadIdx.x & 63) == 0) atomicAdd(&sums[t], local);
}

// ---------------- level-1 scan: find 14-bit prefix bucket for ranks k and k+1 ----------------
__global__ void scan1_kernel(const unsigned* __restrict__ hist, unsigned* __restrict__ meta_u,
                             const float* __restrict__ sparsity, int n1, int n2) {
    __shared__ unsigned partial[256];
    __shared__ unsigned basearr[256];
    for (int t = 0; t < 2; t++) {
        const unsigned* h = hist + (size_t)t * L1_SIZE;
        int n = t ? n2 : n1;
        double p = (double)(*sparsity) * (double)(n - 1);
        unsigned kA = (unsigned)floor(p);
        unsigned kB = kA + 1; if (kB > (unsigned)(n - 1)) kB = (unsigned)(n - 1);
        int b0 = threadIdx.x * (L1_SIZE / 256);
        unsigned s_local = 0;
        for (int b = 0; b < L1_SIZE / 256; b++) s_local += h[b0 + b];
        partial[threadIdx.x] = s_local;
        __syncthreads();
        if (threadIdx.x == 0) {
            unsigned run = 0;
            for (int i = 0; i < 256; i++) { unsigned tmp = partial[i]; basearr[i] = run; run += tmp; }
        }
        __syncthreads();
        unsigned cumbase = basearr[threadIdx.x];
        for (int s = 0; s < 2; s++) {
            unsigned rank = s ? kB : kA;
            if (rank >= cumbase && rank < cumbase + s_local) {
                unsigned cum = cumbase;
                for (int b = 0; b < L1_SIZE / 256; b++) {
                    unsigned c = h[b0 + b];
                    if (rank < cum + c) { meta_u[s * 4 + t] = (unsigned)(b0 + b); meta_u[s * 4 + 2 + t] = rank - cum; break; }
                    cum += c;
                }
            }
        }
        __syncthreads();
    }
}

// ---------------- level-2 histogram (low 18 bits) restricted to selected prefixes ----------------
__global__ void hist2_kernel(const float* __restrict__ W1, int n1,
                             const float* __restrict__ W2, int n2,
                             const unsigned* __restrict__ meta_u, unsigned* __restrict__ hist2) {
    int tid = blockIdx.x * blockDim.x + threadIdx.x;
    int stride = gridDim.x * blockDim.x;
    for (int t = 0; t < 2; t++) {
        const float* W = t ? W2 : W1;
        int n = t ? n2 : n1;
        unsigned pa = meta_u[0 + t], pb = meta_u[4 + t];
        unsigned* hA = hist2 + (size_t)(t * 2 + 0) * L2_SIZE;
        unsigned* hB = hist2 + (size_t)(t * 2 + 1) * L2_SIZE;
        int n4 = n >> 2;
        for (int i = tid; i < n4; i += stride) {
            f32x4 w = ((const f32x4*)W)[i];
#pragma unroll
            for (int j = 0; j < 4; j++) {
                unsigned u = __float_as_uint(fabsf(w[j]));
                unsigned hi = u >> (32 - L1_BITS);
                if (hi == pa) atomicAdd(&hA[u & L2_MASK], 1u);
                if (hi == pb) atomicAdd(&hB[u & L2_MASK], 1u);
            }
        }
        for (int i = (n4 << 2) + tid; i < n; i += stride) {
            unsigned u = __float_as_uint(fabsf(W[i]));
            unsigned hi = u >> (32 - L1_BITS);
            if (hi == pa) atomicAdd(&hA[u & L2_MASK], 1u);
            if (hi == pb) atomicAdd(&hB[u & L2_MASK], 1u);
        }
    }
}

// ---------------- level-2 scan: exact order stats -> fp64 threshold + scale ----------------
__global__ void scan2_kernel(const unsigned* __restrict__ hist2, unsigned* __restrict__ meta_u,
                             const double* __restrict__ sums, const float* __restrict__ sparsity,
                             double* __restrict__ thr, int n1, int n2) {
    __shared__ unsigned partial[256];
    __shared__ unsigned basearr[256];
    __shared__ unsigned vb[2];
    float* meta_f = (float*)meta_u;
    for (int t = 0; t < 2; t++) {
        int n = t ? n2 : n1;
        for (int s = 0; s < 2; s++) {
            const unsigned* h = hist2 + (size_t)(t * 2 + s) * L2_SIZE;
            unsigned rank = meta_u[s * 4 + 2 + t];
            unsigned pfx = meta_u[s * 4 + t];
            int b0 = threadIdx.x * (L2_SIZE / 256);
            unsigned s_local = 0;
            for (int b = 0; b < L2_SIZE / 256; b++) s_local += h[b0 + b];
            partial[threadIdx.x] = s_local;
            __syncthreads();
            if (threadIdx.x == 0) {
                unsigned run = 0;
                for (int i = 0; i < 256; i++) { unsigned tmp = partial[i]; basearr[i] = run; run += tmp; }
            }
            __syncthreads();
            unsigned cumbase = basearr[threadIdx.x];
            if (rank >= cumbase && rank < cumbase + s_local) {
                unsigned cum = cumbase;
                for (int b = 0; b < L2_SIZE / 256; b++) {
                    unsigned c = h[b0 + b];
                    if (rank < cum + c) { vb[s] = (pfx << (32 - L1_BITS)) | (unsigned)(b0 + b); break; }
                    cum += c;
                }
            }
            __syncthreads();
        }
        if (threadIdx.x == 0) {
            double a = (double)__uint_as_float(vb[0]);
            double b = (double)__uint_as_float(vb[1]);
            double p = (double)(*sparsity) * (double)(n - 1);
            double tfr = p - floor(p);
            double th = (tfr >= 0.5) ? (b - (b - a) * (1.0 - tfr)) : (a + (b - a) * tfr);
            thr[t] = th;
            meta_f[8 + t] = (float)(sums[t] / (double)n);
        }
        __syncthreads();
    }
}

// ---------------- ternary quantize W -> bf16 {-1,0,+1} ----------------
__global__ void quantize_kernel(const float* __restrict__ W1, int n1,
                                const float* __restrict__ W2, int n2,
                                const double* __restrict__ thr,
                                unsigned short* __restrict__ wq1, unsigned short* __restrict__ wq2) {
    int tid = blockIdx.x * blockDim.x + threadIdx.x;
    int stride = gridDim.x * blockDim.x;
    for (int t = 0; t < 2; t++) {
        const float* W = t ? W2 : W1;
        unsigned short* O = t ? wq2 : wq1;
        int n = t ? n2 : n1;
        double th = thr[t];
        int n4 = n >> 2;
        for (int i = tid; i < n4; i += stride) {
            f32x4 w = ((const f32x4*)W)[i];
            ushort4v q;
#pragma unroll
            for (int j = 0; j < 4; j++) {
                float a = fabsf(w[j]);
                unsigned short v = 0;
                if ((double)a > th) v = (w[j] > 0.f) ? 0x3F80u : 0xBF80u;
                q[j] = v;
            }
            ((ushort4v*)O)[i] = q;
        }
        for (int i = (n4 << 2) + tid; i < n; i += stride) {
            float wv = W[i];
            float a = fabsf(wv);
            unsigned short v = 0;
            if ((double)a > th) v = (wv > 0.f) ? 0x3F80u : 0xBF80u;
            O[i] = v;
        }
    }
}

// ---------------- LN1: stats + apply, write xn bf16 (D=768), one wave per row ----------------
__global__ void ln1_apply_kernel(const float* __restrict__ x, const float* __restrict__ g,
                                 const float* __restrict__ b, unsigned short* __restrict__ xn, int M) {
    int wave = threadIdx.x >> 6, lane = threadIdx.x & 63;
    int row = blockIdx.x * 4 + wave;
    if (row >= M) return;
    const float* xr = x + (size_t)row * D_DIM;
    f32x4 xv[3];
    float s = 0.f, s2 = 0.f;
#pragma unroll
    for (int i = 0; i < 3; i++) {
        xv[i] = *(const f32x4*)&xr[lane * 4 + i * 256];
#pragma unroll
        for (int j = 0; j < 4; j++) { s += xv[i][j]; s2 += xv[i][j] * xv[i][j]; }
    }
#pragma unroll
    for (int off = 32; off >= 1; off >>= 1) { s += __shfl_xor(s, off); s2 += __shfl_xor(s2, off); }
    float m = s / (float)D_DIM;
    float var = s2 / (float)D_DIM - m * m;
    float rs = 1.f / sqrtf(var + 1e-5f);
    unsigned short* xo = xn + (size_t)row * D_DIM;
#pragma unroll
    for (int i = 0; i < 3; i++) {
        int k = lane * 4 + i * 256;
        f32x4 gg = *(const f32x4*)&g[k];
        f32x4 bb = *(const f32x4*)&b[k];
        ushort4v o;
#pragma unroll
        for (int j = 0; j < 4; j++) o[j] = f2bf((xv[i][j] - m) * rs * gg[j] + bb[j]);
        *(ushort4v*)&xo[k] = o;
    }
}

// ---------------- LN2: stats + apply IN-PLACE on h1 bf16 (H=3072), one wave per row --------
__global__ void ln2_fuse_kernel(unsigned short* __restrict__ h1, const float* __restrict__ g,
                                const float* __restrict__ b, int M) {
    int wave = threadIdx.x >> 6, lane = threadIdx.x & 63;
    int row = blockIdx.x * 4 + wave;
    if (row >= M) return;
    unsigned short* hr = h1 + (size_t)row * H_DIM;
    ushort8 hv[6];
    float s = 0.f, s2 = 0.f;
#pragma unroll
    for (int i = 0; i < 6; i++) {
        hv[i] = *(const ushort8*)&hr[lane * 8 + i * 512];
#pragma unroll
        for (int j = 0; j < 8; j++) { float f = bf2f(hv[i][j]); s += f; s2 += f * f; }
    }
#pragma unroll
    for (int off = 32; off >= 1; off >>= 1) { s += __shfl_xor(s, off); s2 += __shfl_xor(s2, off); }
    float m = s / (float)H_DIM;
    float var = s2 / (float)H_DIM - m * m;
    float rs = 1.f / sqrtf(var + 1e-5f);
#pragma unroll
    for (int i = 0; i < 6; i++) {
        int k = lane * 8 + i * 512;
        f32x4 ga = *(const f32x4*)&g[k];
        f32x4 gb = *(const f32x4*)&g[k + 4];
        f32x4 ba = *(const f32x4*)&b[k];
        f32x4 bb = *(const f32x4*)&b[k + 4];
        ushort8 o;
#pragma unroll
        for (int j = 0; j < 4; j++) o[j]     = f2bf((bf2f(hv[i][j])     - m) * rs * ga[j] + ba[j]);
#pragma unroll
        for (int j = 0; j < 4; j++) o[4 + j] = f2bf((bf2f(hv[i][4 + j]) - m) * rs * gb[j] + bb[j]);
        *(ushort8*)&hr[k] = o;
    }
}

// ---------------- pure bf16 GEMM: C = A @ Bq^T (both row-major, K contiguous) --------------
// 128x128 tile, BK=64, global_load_lds(16B) with XOR-8 chunk swizzle (linear LDS dest,
// inverse-swizzled global source, swizzled ds_read) -> conflict-free b128 fragment reads.
// EPI 1: h1 = bf16(gelu(acc*scale + bias)), out stride H_DIM.
// EPI 2: out = fp32(acc*scale + bias), out stride D_DIM.
template<int KD, int EPI>
__launch_bounds__(256)
__global__ void gemm_tern_kernel(const unsigned short* __restrict__ A,
                                 const unsigned short* __restrict__ Bq,
                                 const float* __restrict__ bias,
                                 const float* __restrict__ meta_f, int sidx,
                                 void* __restrict__ outp) {
    __shared__ unsigned short As[128 * 64];
    __shared__ unsigned short Bs[128 * 64];
    const int m0 = blockIdx.y * 128, n0 = blockIdx.x * 128;
    const float scale = meta_f[sidx];
    const int tt = threadIdx.x, lane = tt & 63, wave = tt >> 6;
    const int wm = (wave & 1) * 64, wn = (wave >> 1) * 64;
    const int l16 = lane & 15, l4 = lane >> 4;
    const int srow = tt >> 3, schunk = tt & 7;

    f32x4 acc[4][4];
#pragma unroll
    for (int mi = 0; mi < 4; mi++)
#pragma unroll
        for (int ni = 0; ni < 4; ni++) acc[mi][ni] = (f32x4){0.f, 0.f, 0.f, 0.f};

    for (int k0 = 0; k0 < KD; k0 += 64) {
#pragma unroll
        for (int r = 0; r < 4; r++) {
            int row = r * 32 + srow;
            int sc = (schunk ^ (row & 7)) << 3;              // inverse-swizzled source col (elems)
            gload16(&A[(size_t)(m0 + row) * KD + k0 + sc], &As[(size_t)tt * 8 + r * 2048]);
        }
#pragma unroll
        for (int r = 0; r < 4; r++) {
            int row = r * 32 + srow;
            int sc = (schunk ^ (row & 7)) << 3;
            gload16(&Bq[(size_t)(n0 + row) * KD + k0 + sc], &Bs[(size_t)tt * 8 + r * 2048]);
        }
        __syncthreads();   // compiler drains vmcnt(0) before s_barrier
#pragma unroll
        for (int ks = 0; ks < 2; ks++) {
            short8 af[4], bf_[4];
#pragma unroll
            for (int i = 0; i < 4; i++) {
                int ar = wm + i * 16 + l16;
                af[i] = *(const short8*)&As[ar * 64 + (((ks * 4 + l4) ^ (ar & 7)) << 3)];
                int br = wn + i * 16 + l16;
                bf_[i] = *(const short8*)&Bs[br * 64 + (((ks * 4 + l4) ^ (br & 7)) << 3)];
            }
#pragma unroll
            for (int mi = 0; mi < 4; mi++)
#pragma unroll
                for (int ni = 0; ni < 4; ni++)
                    acc[mi][ni] = __builtin_amdgcn_mfma_f32_16x16x32_bf16(af[mi], bf_[ni], acc[mi][ni], 0, 0, 0);
        }
        __syncthreads();
    }

#pragma unroll
    for (int ni = 0; ni < 4; ni++) {
        int col = n0 + wn + ni * 16 + l16;
        float bl = bias[col];
#pragma unroll
        for (int mi = 0; mi < 4; mi++) {
#pragma unroll
            for (int j = 0; j < 4; j++) {
                int row = m0 + wm + mi * 16 + l4 * 4 + j;
                float v = acc[mi][ni][j] * scale + bl;
                if constexpr (EPI == 1) {
                    // gelu(v) = v * sigmoid(1.5957691*(v+0.044715 v^3))  (== tanh form)
                    float y = 1.5957691216f * (v + 0.044715f * v * v * v);
                    float e = exp2f(-1.4426950409f * y);
                    float gel = v / (1.f + e);
                    ((unsigned short*)outp)[(size_t)row * H_DIM + col] = f2bf(gel);
                } else {
                    ((float*)outp)[(size_t)row * D_DIM + col] = v;
                }
            }
        }
    }
}

extern "C" void kernel_launch(void* const* d_in, const int* in_sizes, int n_in,
                              void* d_out, int out_size, void* d_ws, size_t ws_size,
                              hipStream_t stream) {
    const float* x    = (const float*)d_in[0];
    const float* ln1g = (const float*)d_in[1];
    const float* ln1b = (const float*)d_in[2];
    const float* W1   = (const float*)d_in[3];
    const float* b1   = (const float*)d_in[4];
    const float* ln2g = (const float*)d_in[5];
    const float* ln2b = (const float*)d_in[6];
    const float* W2   = (const float*)d_in[7];
    const float* b2   = (const float*)d_in[8];
    const float* sp   = (const float*)d_in[9];
    const int n1 = in_sizes[3], n2 = in_sizes[7];
    const int M = in_sizes[0] / D_DIM;

    char* ws = (char*)d_ws;
    unsigned* hist1 = (unsigned*)(ws + HIST1_OFF);
    unsigned* hist2 = (unsigned*)(ws + HIST2_OFF);
    double*   sums  = (double*)(ws + SUM_OFF);
    double*   thr   = (double*)(ws + THR_OFF);
    unsigned* meta_u = (unsigned*)(ws + META_OFF);
    float*    meta_f = (float*)(ws + META_OFF);
    unsigned short* wq1 = (unsigned short*)(ws + WQ1_OFF);
    unsigned short* wq2 = (unsigned short*)(ws + WQ2_OFF);
    unsigned short* h1  = (unsigned short*)(ws + H1_OFF);
    unsigned short* xn  = (unsigned short*)d_out;   // scratch: overwritten by gemm2 at the end

    hipMemsetAsync(d_ws, 0, ZERO_BYTES, stream);
    hist_abs_kernel<<<dim3(512, 2), 256, 0, stream>>>(W1, n1, W2, n2, hist1, sums);
    scan1_kernel<<<1, 256, 0, stream>>>(hist1, meta_u, sp, n1, n2);
    hist2_kernel<<<2048, 256, 0, stream>>>(W1, n1, W2, n2, meta_u, hist2);
    scan2_kernel<<<1, 256, 0, stream>>>(hist2, meta_u, sums, sp, thr, n1, n2);
    quantize_kernel<<<2048, 256, 0, stream>>>(W1, n1, W2, n2, thr, wq1, wq2);
    ln1_apply_kernel<<<M / 4, 256, 0, stream>>>(x, ln1g, ln1b, xn, M);
    gemm_tern_kernel<D_DIM, 1><<<dim3(H_DIM / 128, M / 128), 256, 0, stream>>>(xn, wq1, b1, meta_f, 8, h1);
    ln2_fuse_kernel<<<M / 4, 256, 0, stream>>>(h1, ln2g, ln2b, M);
    gemm_tern_kernel<H_DIM, 2><<<dim3(D_DIM / 128, M / 128), 256, 0, stream>>>(h1, wq2, b2, meta_f, 9, d_out);
}

// Round 7
// 792.803 us; speedup vs baseline: 2.7951x; 1.3466x over previous
//
#include <hip/hip_runtime.h>
#include <math.h>

using f32x4    = __attribute__((ext_vector_type(4))) float;
using short8   = __attribute__((ext_vector_type(8))) short;
using ushort8  = __attribute__((ext_vector_type(8))) unsigned short;
using ushort4v = __attribute__((ext_vector_type(4))) unsigned short;
using u32x4    = __attribute__((ext_vector_type(4))) unsigned int;

#define D_DIM 768
#define H_DIM 3072

// 3-level radix select on |w| bit pattern: 14 + 9 + 9 bits.
// L1: 16384 buckets (LDS-privatized). L2/L3: 512 buckets x 4 (t,s) slots (LDS-privatized).
#define L1_BITS 14
#define L1_SIZE 16384

// ---------------- ws layout (bytes) ----------------
static const size_t HIST1_OFF = 0;                        // 2*16384*4 = 131072
static const size_t HIST2_OFF = 131072;                   // 4*512*4 = 8192 -> 139264
static const size_t HIST3_OFF = 139264;                   // 8192 -> 147456
static const size_t SUM_OFF   = 147456;                   // double[2] -> 147472
static const size_t THR_OFF   = 147472;                   // double[2] -> 147488
static const size_t META_OFF  = 147488;                   // u32[32]  -> 147616
static const size_t ZERO_BYTES= 147616;
static const size_t WQ1_OFF   = 5242880;                  // bf16[3072*768] = 4718592
static const size_t WQ2_OFF   = WQ1_OFF + 4718592;        // end 14680064
static const size_t H1_OFF    = 16777216;                 // bf16[32768*3072] = 201326592
// xn (bf16 LN1(x), 48 MB) lives in d_out until gemm2 overwrites it (stream-ordered).

// meta_u: [0..7]   L1 result:  [s*4+t]=pfx14,  [s*4+2+t]=rem
//         [16..23] L2 result:  [16+s*4+t]=pfx23, [16+s*4+2+t]=rem2
//         [24..25] (f32 view) scale[t]

__device__ __forceinline__ unsigned short f2bf(float f) {
    unsigned u = __float_as_uint(f);
    u += 0x7fffu + ((u >> 16) & 1u);
    return (unsigned short)(u >> 16);
}
__device__ __forceinline__ float bf2f(unsigned short s) {
    return __uint_as_float(((unsigned)s) << 16);
}

// async global->LDS, 16 B per lane. LDS dest must be wave-uniform base + lane*16.
__device__ __forceinline__ void gload16(const unsigned short* g, unsigned short* l) {
    __builtin_amdgcn_global_load_lds(
        (const __attribute__((address_space(1))) unsigned int*)g,
        (__attribute__((address_space(3))) unsigned int*)l, 16, 0, 0);
}

// ---------------- L1: LDS-privatized 14-bit histogram of |w| + fp64 abs-sum ----------------
__global__ void hist_abs_kernel(const float* __restrict__ W1, int n1,
                                const float* __restrict__ W2, int n2,
                                unsigned* __restrict__ hist, double* __restrict__ sums) {
    __shared__ unsigned lh[L1_SIZE];
    const int t = blockIdx.y;
    const float* W = t ? W2 : W1;
    const int n = t ? n2 : n1;
    unsigned* hg = hist + (size_t)t * L1_SIZE;

    for (int i = threadIdx.x; i < L1_SIZE; i += 256) lh[i] = 0;
    __syncthreads();

    int tid = blockIdx.x * blockDim.x + threadIdx.x;
    int stride = gridDim.x * blockDim.x;
    double local = 0.0;
    int n4 = n >> 2;
    for (int i = tid; i < n4; i += stride) {
        f32x4 w = ((const f32x4*)W)[i];
#pragma unroll
        for (int j = 0; j < 4; j++) {
            float a = fabsf(w[j]);
            local += (double)a;
            atomicAdd(&lh[__float_as_uint(a) >> (32 - L1_BITS)], 1u);
        }
    }
    for (int i = (n4 << 2) + tid; i < n; i += stride) {
        float a = fabsf(W[i]);
        local += (double)a;
        atomicAdd(&lh[__float_as_uint(a) >> (32 - L1_BITS)], 1u);
    }
    __syncthreads();
    for (int i = threadIdx.x; i < L1_SIZE; i += 256) {
        unsigned c = lh[i];
        if (c) atomicAdd(&hg[i], c);
    }
#pragma unroll
    for (int off = 32; off >= 1; off >>= 1) local += __shfl_down(local, off);
    if ((threadIdx.x & 63) == 0) atomicAdd(&sums[t], local);
}

// ---------------- L1 scan: find 14-bit prefix bucket for ranks k and k+1 ----------------
__global__ void scan1_kernel(const unsigned* __restrict__ hist, unsigned* __restrict__ meta_u,
                             const float* __restrict__ sparsity, int n1, int n2) {
    __shared__ unsigned partial[256];
    __shared__ unsigned basearr[256];
    for (int t = 0; t < 2; t++) {
        const unsigned* h = hist + (size_t)t * L1_SIZE;
        int n = t ? n2 : n1;
        double p = (double)(*sparsity) * (double)(n - 1);
        unsigned kA = (unsigned)floor(p);
        unsigned kB = kA + 1; if (kB > (unsigned)(n - 1)) kB = (unsigned)(n - 1);
        int b0 = threadIdx.x * 64;
        unsigned s_local = 0;
#pragma unroll
        for (int b = 0; b < 64; b += 4) {
            u32x4 v = *(const u32x4*)&h[b0 + b];
            s_local += v[0] + v[1] + v[2] + v[3];
        }
        partial[threadIdx.x] = s_local;
        __syncthreads();
        if (threadIdx.x == 0) {
            unsigned run = 0;
            for (int i = 0; i < 256; i++) { unsigned tmp = partial[i]; basearr[i] = run; run += tmp; }
        }
        __syncthreads();
        unsigned cumbase = basearr[threadIdx.x];
        for (int s = 0; s < 2; s++) {
            unsigned rank = s ? kB : kA;
            if (rank >= cumbase && rank < cumbase + s_local) {
                unsigned cum = cumbase;
                for (int b = 0; b < 64; b++) {
                    unsigned c = h[b0 + b];
                    if (rank < cum + c) { meta_u[s * 4 + t] = (unsigned)(b0 + b); meta_u[s * 4 + 2 + t] = rank - cum; break; }
                    cum += c;
                }
            }
        }
        __syncthreads();
    }
}

// ---------------- L2/L3: 512-bucket LDS-privatized histogram restricted to prefix ----------
// LVL=2: match top-14 bits, index next 9. LVL=3: match top-23 bits, index low 9.
template<int LVL>
__global__ void histN_kernel(const float* __restrict__ W1, int n1,
                             const float* __restrict__ W2, int n2,
                             const unsigned* __restrict__ meta_u, unsigned* __restrict__ histo) {
    __shared__ unsigned hA[512], hB[512];
    const int t = blockIdx.y;
    const float* W = t ? W2 : W1;
    const int n = t ? n2 : n1;
    for (int i = threadIdx.x; i < 512; i += 256) { hA[i] = 0; hB[i] = 0; }
    __syncthreads();
    const int inbase = (LVL == 2) ? 0 : 16;
    unsigned pa = meta_u[inbase + 0 + t], pb = meta_u[inbase + 4 + t];
    int tid = blockIdx.x * blockDim.x + threadIdx.x;
    int stride = gridDim.x * blockDim.x;
    int n4 = n >> 2;
    for (int i = tid; i < n4; i += stride) {
        f32x4 w = ((const f32x4*)W)[i];
#pragma unroll
        for (int j = 0; j < 4; j++) {
            unsigned u = __float_as_uint(fabsf(w[j]));
            unsigned pf  = (LVL == 2) ? (u >> 18) : (u >> 9);
            unsigned idx = (LVL == 2) ? ((u >> 9) & 0x1FFu) : (u & 0x1FFu);
            if (pf == pa) atomicAdd(&hA[idx], 1u);
            if (pf == pb) atomicAdd(&hB[idx], 1u);
        }
    }
    for (int i = (n4 << 2) + tid; i < n; i += stride) {
        unsigned u = __float_as_uint(fabsf(W[i]));
        unsigned pf  = (LVL == 2) ? (u >> 18) : (u >> 9);
        unsigned idx = (LVL == 2) ? ((u >> 9) & 0x1FFu) : (u & 0x1FFu);
        if (pf == pa) atomicAdd(&hA[idx], 1u);
        if (pf == pb) atomicAdd(&hB[idx], 1u);
    }
    __syncthreads();
    for (int i = threadIdx.x; i < 512; i += 256) {
        unsigned a = hA[i]; if (a) atomicAdd(&histo[(size_t)(t * 2 + 0) * 512 + i], a);
        unsigned b = hB[i]; if (b) atomicAdd(&histo[(size_t)(t * 2 + 1) * 512 + i], b);
    }
}

// ---------------- L2 scan: one wave per (t,s); shfl prefix-scan over 512 buckets ------------
__global__ void scan_mid_kernel(const unsigned* __restrict__ histo, unsigned* __restrict__ meta_u) {
    int wave = threadIdx.x >> 6, lane = threadIdx.x & 63;
    int s = wave >> 1, t = wave & 1;
    const unsigned* h = histo + (size_t)(t * 2 + s) * 512;
    unsigned rank = meta_u[s * 4 + 2 + t];
    unsigned pfx  = meta_u[s * 4 + t];
    u32x4 ca = *(const u32x4*)&h[lane * 8];
    u32x4 cb = *(const u32x4*)&h[lane * 8 + 4];
    unsigned cc[8] = {ca[0], ca[1], ca[2], ca[3], cb[0], cb[1], cb[2], cb[3]};
    unsigned csum = cc[0] + cc[1] + cc[2] + cc[3] + cc[4] + cc[5] + cc[6] + cc[7];
    unsigned inc = csum;
#pragma unroll
    for (int off = 1; off < 64; off <<= 1) {
        unsigned v = __shfl_up(inc, off, 64);
        if (lane >= off) inc += v;
    }
    unsigned pre = inc - csum;
    if (rank >= pre && rank < pre + csum) {
        unsigned cum = pre, rem = 0, bucket = 0; bool found = false;
#pragma unroll
        for (int j = 0; j < 8; j++) {
            if (!found) {
                if (rank < cum + cc[j]) { bucket = lane * 8 + j; rem = rank - cum; found = true; }
                else cum += cc[j];
            }
        }
        meta_u[16 + s * 4 + t] = (pfx << 9) | bucket;
        meta_u[16 + s * 4 + 2 + t] = rem;
    }
}

// ---------------- L3 scan: exact order stats -> fp64 threshold + scale ----------------------
__global__ void scan_fin_kernel(const unsigned* __restrict__ histo, unsigned* __restrict__ meta_u,
                                const double* __restrict__ sums, const float* __restrict__ sparsity,
                                double* __restrict__ thr, int n1, int n2) {
    __shared__ unsigned vbs[4];
    int wave = threadIdx.x >> 6, lane = threadIdx.x & 63;
    int s = wave >> 1, t = wave & 1;
    const unsigned* h = histo + (size_t)(t * 2 + s) * 512;
    unsigned rank = meta_u[16 + s * 4 + 2 + t];
    unsigned pfx  = meta_u[16 + s * 4 + t];
    u32x4 ca = *(const u32x4*)&h[lane * 8];
    u32x4 cb = *(const u32x4*)&h[lane * 8 + 4];
    unsigned cc[8] = {ca[0], ca[1], ca[2], ca[3], cb[0], cb[1], cb[2], cb[3]};
    unsigned csum = cc[0] + cc[1] + cc[2] + cc[3] + cc[4] + cc[5] + cc[6] + cc[7];
    unsigned inc = csum;
#pragma unroll
    for (int off = 1; off < 64; off <<= 1) {
        unsigned v = __shfl_up(inc, off, 64);
        if (lane >= off) inc += v;
    }
    unsigned pre = inc - csum;
    if (rank >= pre && rank < pre + csum) {
        unsigned cum = pre, bucket = 0; bool found = false;
#pragma unroll
        for (int j = 0; j < 8; j++) {
            if (!found) {
                if (rank < cum + cc[j]) { bucket = lane * 8 + j; found = true; }
                else cum += cc[j];
            }
        }
        vbs[t * 2 + s] = (pfx << 9) | bucket;
    }
    __syncthreads();
    if (threadIdx.x < 2) {
        int tt = threadIdx.x;
        int n = tt ? n2 : n1;
        double a = (double)__uint_as_float(vbs[tt * 2 + 0]);
        double b = (double)__uint_as_float(vbs[tt * 2 + 1]);
        double p = (double)(*sparsity) * (double)(n - 1);
        double tfr = p - floor(p);
        double th = (tfr >= 0.5) ? (b - (b - a) * (1.0 - tfr)) : (a + (b - a) * tfr);
        thr[tt] = th;
        ((float*)meta_u)[24 + tt] = (float)(sums[tt] / (double)n);
    }
}

// ---------------- ternary quantize W -> bf16 {-1,0,+1} ----------------
__global__ void quantize_kernel(const float* __restrict__ W1, int n1,
                                const float* __restrict__ W2, int n2,
                                const double* __restrict__ thr,
                                unsigned short* __restrict__ wq1, unsigned short* __restrict__ wq2) {
    int tid = blockIdx.x * blockDim.x + threadIdx.x;
    int stride = gridDim.x * blockDim.x;
    for (int t = 0; t < 2; t++) {
        const float* W = t ? W2 : W1;
        unsigned short* O = t ? wq2 : wq1;
        int n = t ? n2 : n1;
        double th = thr[t];
        int n4 = n >> 2;
        for (int i = tid; i < n4; i += stride) {
            f32x4 w = ((const f32x4*)W)[i];
            ushort4v q;
#pragma unroll
            for (int j = 0; j < 4; j++) {
                float a = fabsf(w[j]);
                unsigned short v = 0;
                if ((double)a > th) v = (w[j] > 0.f) ? 0x3F80u : 0xBF80u;
                q[j] = v;
            }
            ((ushort4v*)O)[i] = q;
        }
        for (int i = (n4 << 2) + tid; i < n; i += stride) {
            float wv = W[i];
            float a = fabsf(wv);
            unsigned short v = 0;
            if ((double)a > th) v = (wv > 0.f) ? 0x3F80u : 0xBF80u;
            O[i] = v;
        }
    }
}

// ---------------- LN1: stats + apply, write xn bf16 (D=768), one wave per row ----------------
__global__ void ln1_apply_kernel(const float* __restrict__ x, const float* __restrict__ g,
                                 const float* __restrict__ b, unsigned short* __restrict__ xn, int M) {
    int wave = threadIdx.x >> 6, lane = threadIdx.x & 63;
    int row = blockIdx.x * 4 + wave;
    if (row >= M) return;
    const float* xr = x + (size_t)row * D_DIM;
    f32x4 xv[3];
    float s = 0.f, s2 = 0.f;
#pragma unroll
    for (int i = 0; i < 3; i++) {
        xv[i] = *(const f32x4*)&xr[lane * 4 + i * 256];
#pragma unroll
        for (int j = 0; j < 4; j++) { s += xv[i][j]; s2 += xv[i][j] * xv[i][j]; }
    }
#pragma unroll
    for (int off = 32; off >= 1; off >>= 1) { s += __shfl_xor(s, off); s2 += __shfl_xor(s2, off); }
    float m = s / (float)D_DIM;
    float var = s2 / (float)D_DIM - m * m;
    float rs = 1.f / sqrtf(var + 1e-5f);
    unsigned short* xo = xn + (size_t)row * D_DIM;
#pragma unroll
    for (int i = 0; i < 3; i++) {
        int k = lane * 4 + i * 256;
        f32x4 gg = *(const f32x4*)&g[k];
        f32x4 bb = *(const f32x4*)&b[k];
        ushort4v o;
#pragma unroll
        for (int j = 0; j < 4; j++) o[j] = f2bf((xv[i][j] - m) * rs * gg[j] + bb[j]);
        *(ushort4v*)&xo[k] = o;
    }
}

// ---------------- LN2: stats + apply IN-PLACE on h1 bf16 (H=3072), one wave per row --------
__global__ void ln2_fuse_kernel(unsigned short* __restrict__ h1, const float* __restrict__ g,
                                const float* __restrict__ b, int M) {
    int wave = threadIdx.x >> 6, lane = threadIdx.x & 63;
    int row = blockIdx.x * 4 + wave;
    if (row >= M) return;
    unsigned short* hr = h1 + (size_t)row * H_DIM;
    ushort8 hv[6];
    float s = 0.f, s2 = 0.f;
#pragma unroll
    for (int i = 0; i < 6; i++) {
        hv[i] = *(const ushort8*)&hr[lane * 8 + i * 512];
#pragma unroll
        for (int j = 0; j < 8; j++) { float f = bf2f(hv[i][j]); s += f; s2 += f * f; }
    }
#pragma unroll
    for (int off = 32; off >= 1; off >>= 1) { s += __shfl_xor(s, off); s2 += __shfl_xor(s2, off); }
    float m = s / (float)H_DIM;
    float var = s2 / (float)H_DIM - m * m;
    float rs = 1.f / sqrtf(var + 1e-5f);
#pragma unroll
    for (int i = 0; i < 6; i++) {
        int k = lane * 8 + i * 512;
        f32x4 ga = *(const f32x4*)&g[k];
        f32x4 gb = *(const f32x4*)&g[k + 4];
        f32x4 ba = *(const f32x4*)&b[k];
        f32x4 bb = *(const f32x4*)&b[k + 4];
        ushort8 o;
#pragma unroll
        for (int j = 0; j < 4; j++) o[j]     = f2bf((bf2f(hv[i][j])     - m) * rs * ga[j] + ba[j]);
#pragma unroll
        for (int j = 0; j < 4; j++) o[4 + j] = f2bf((bf2f(hv[i][4 + j]) - m) * rs * gb[j] + bb[j]);
        *(ushort8*)&hr[k] = o;
    }
}

// ---------------- pure bf16 GEMM: C = A @ Bq^T (both row-major, K contiguous) --------------
// 128x128 tile, BK=64, global_load_lds(16B) with XOR-8 chunk swizzle (linear LDS dest,
// inverse-swizzled global source, swizzled ds_read) -> conflict-free b128 fragment reads.
template<int KD, int EPI>
__launch_bounds__(256)
__global__ void gemm_tern_kernel(const unsigned short* __restrict__ A,
                                 const unsigned short* __restrict__ Bq,
                                 const float* __restrict__ bias,
                                 const float* __restrict__ meta_f, int sidx,
                                 void* __restrict__ outp) {
    __shared__ unsigned short As[128 * 64];
    __shared__ unsigned short Bs[128 * 64];
    const int m0 = blockIdx.y * 128, n0 = blockIdx.x * 128;
    const float scale = meta_f[sidx];
    const int tt = threadIdx.x, lane = tt & 63, wave = tt >> 6;
    const int wm = (wave & 1) * 64, wn = (wave >> 1) * 64;
    const int l16 = lane & 15, l4 = lane >> 4;
    const int srow = tt >> 3, schunk = tt & 7;

    f32x4 acc[4][4];
#pragma unroll
    for (int mi = 0; mi < 4; mi++)
#pragma unroll
        for (int ni = 0; ni < 4; ni++) acc[mi][ni] = (f32x4){0.f, 0.f, 0.f, 0.f};

    for (int k0 = 0; k0 < KD; k0 += 64) {
#pragma unroll
        for (int r = 0; r < 4; r++) {
            int row = r * 32 + srow;
            int sc = (schunk ^ (row & 7)) << 3;              // inverse-swizzled source col (elems)
            gload16(&A[(size_t)(m0 + row) * KD + k0 + sc], &As[(size_t)tt * 8 + r * 2048]);
        }
#pragma unroll
        for (int r = 0; r < 4; r++) {
            int row = r * 32 + srow;
            int sc = (schunk ^ (row & 7)) << 3;
            gload16(&Bq[(size_t)(n0 + row) * KD + k0 + sc], &Bs[(size_t)tt * 8 + r * 2048]);
        }
        __syncthreads();   // compiler drains vmcnt(0) before s_barrier
#pragma unroll
        for (int ks = 0; ks < 2; ks++) {
            short8 af[4], bf_[4];
#pragma unroll
            for (int i = 0; i < 4; i++) {
                int ar = wm + i * 16 + l16;
                af[i] = *(const short8*)&As[ar * 64 + (((ks * 4 + l4) ^ (ar & 7)) << 3)];
                int br = wn + i * 16 + l16;
                bf_[i] = *(const short8*)&Bs[br * 64 + (((ks * 4 + l4) ^ (br & 7)) << 3)];
            }
#pragma unroll
            for (int mi = 0; mi < 4; mi++)
#pragma unroll
                for (int ni = 0; ni < 4; ni++)
                    acc[mi][ni] = __builtin_amdgcn_mfma_f32_16x16x32_bf16(af[mi], bf_[ni], acc[mi][ni], 0, 0, 0);
        }
        __syncthreads();
    }

#pragma unroll
    for (int ni = 0; ni < 4; ni++) {
        int col = n0 + wn + ni * 16 + l16;
        float bl = bias[col];
#pragma unroll
        for (int mi = 0; mi < 4; mi++) {
#pragma unroll
            for (int j = 0; j < 4; j++) {
                int row = m0 + wm + mi * 16 + l4 * 4 + j;
                float v = acc[mi][ni][j] * scale + bl;
                if constexpr (EPI == 1) {
                    float y = 1.5957691216f * (v + 0.044715f * v * v * v);
                    float e = exp2f(-1.4426950409f * y);
                    float gel = v / (1.f + e);
                    ((unsigned short*)outp)[(size_t)row * H_DIM + col] = f2bf(gel);
                } else {
                    ((float*)outp)[(size_t)row * D_DIM + col] = v;
                }
            }
        }
    }
}

extern "C" void kernel_launch(void* const* d_in, const int* in_sizes, int n_in,
                              void* d_out, int out_size, void* d_ws, size_t ws_size,
                              hipStream_t stream) {
    const float* x    = (const float*)d_in[0];
    const float* ln1g = (const float*)d_in[1];
    const float* ln1b = (const float*)d_in[2];
    const float* W1   = (const float*)d_in[3];
    const float* b1   = (const float*)d_in[4];
    const float* ln2g = (const float*)d_in[5];
    const float* ln2b = (const float*)d_in[6];
    const float* W2   = (const float*)d_in[7];
    const float* b2   = (const float*)d_in[8];
    const float* sp   = (const float*)d_in[9];
    const int n1 = in_sizes[3], n2 = in_sizes[7];
    const int M = in_sizes[0] / D_DIM;

    char* ws = (char*)d_ws;
    unsigned* hist1 = (unsigned*)(ws + HIST1_OFF);
    unsigned* hist2 = (unsigned*)(ws + HIST2_OFF);
    unsigned* hist3 = (unsigned*)(ws + HIST3_OFF);
    double*   sums  = (double*)(ws + SUM_OFF);
    double*   thr   = (double*)(ws + THR_OFF);
    unsigned* meta_u = (unsigned*)(ws + META_OFF);
    float*    meta_f = (float*)(ws + META_OFF);
    unsigned short* wq1 = (unsigned short*)(ws + WQ1_OFF);
    unsigned short* wq2 = (unsigned short*)(ws + WQ2_OFF);
    unsigned short* h1  = (unsigned short*)(ws + H1_OFF);
    unsigned short* xn  = (unsigned short*)d_out;   // scratch: overwritten by gemm2 at the end

    hipMemsetAsync(d_ws, 0, ZERO_BYTES, stream);
    hist_abs_kernel<<<dim3(512, 2), 256, 0, stream>>>(W1, n1, W2, n2, hist1, sums);
    scan1_kernel<<<1, 256, 0, stream>>>(hist1, meta_u, sp, n1, n2);
    histN_kernel<2><<<dim3(256, 2), 256, 0, stream>>>(W1, n1, W2, n2, meta_u, hist2);
    scan_mid_kernel<<<1, 256, 0, stream>>>(hist2, meta_u);
    histN_kernel<3><<<dim3(256, 2), 256, 0, stream>>>(W1, n1, W2, n2, meta_u, hist3);
    scan_fin_kernel<<<1, 256, 0, stream>>>(hist3, meta_u, sums, sp, thr, n1, n2);
    quantize_kernel<<<2048, 256, 0, stream>>>(W1, n1, W2, n2, thr, wq1, wq2);
    ln1_apply_kernel<<<M / 4, 256, 0, stream>>>(x, ln1g, ln1b, xn, M);
    gemm_tern_kernel<D_DIM, 1><<<dim3(H_DIM / 128, M / 128), 256, 0, stream>>>(xn, wq1, b1, meta_f, 24, h1);
    ln2_fuse_kernel<<<M / 4, 256, 0, stream>>>(h1, ln2g, ln2b, M);
    gemm_tern_kernel<H_DIM, 2><<<dim3(D_DIM / 128, M / 128), 256, 0, stream>>>(h1, wq2, b2, meta_f, 25, d_out);
}